// Round 12
// baseline (106.446 us; speedup 1.0000x reference)
//
#include <hip/hip_runtime.h>
#include <hip/hip_bf16.h>
#include <math.h>

#define B_ROWS 4096
#define D_DIM  256
#define N_TOT  8192            // 2B
#define E2     7.38905609893065f   // exp(2) = diagonal term of the row sum
#define NTILE  64              // 8192 / 128
#define NBLK   (NTILE * (NTILE + 1) / 2)   // 2080 upper-triangle tile pairs
#define NSLOT  128             // 2 sub-slots per tile-row (wave_n / wave_m split)

typedef __attribute__((ext_vector_type(4))) float f32x4;
typedef __attribute__((ext_vector_type(8))) short bf16x8;   // 8 bf16 in 4 VGPRs

__device__ __forceinline__ void async_copy16(const void* gptr, void* lptr) {
    // NOTE: lptr is the WAVE-UNIFORM base; HW scatters lane*16 itself.
    __builtin_amdgcn_global_load_lds(
        (const __attribute__((address_space(1))) unsigned int*)gptr,
        (__attribute__((address_space(3))) unsigned int*)lptr,
        16 /*bytes*/, 0 /*offset*/, 0 /*aux*/);
}

__device__ __forceinline__ unsigned short bf16_bits(float x) {
    __hip_bfloat16 h = __float2bfloat16(x);
    return *reinterpret_cast<unsigned short*>(&h);
}

// ---------------------------------------------------------------------------
// Kernel 1: wave-per-row L2-normalize query & pos -> bf16 Z[8192][256]; per-
// row positive dot to pospart[row]. (R9-proven, frozen.) Block 0 zeroes
// out[0] for the merged reduce's atomic accumulation.
// ---------------------------------------------------------------------------
__global__ __launch_bounds__(256) void norm_kernel(
        const float* __restrict__ q, const float* __restrict__ p,
        __hip_bfloat16* __restrict__ Z, float* __restrict__ pospart,
        float* __restrict__ out) {
    const int t    = threadIdx.x;
    const int wv   = t >> 6;
    const int lane = t & 63;
    const int row  = blockIdx.x * 4 + wv;        // 0..4095
    if (blockIdx.x == 0 && t == 0) out[0] = 0.0f;

    const f32x4 qv = *(const f32x4*)(q + (size_t)row * D_DIM + lane * 4);
    const f32x4 pv = *(const f32x4*)(p + (size_t)row * D_DIM + lane * 4);
    float a = qv[0]*qv[0] + qv[1]*qv[1] + qv[2]*qv[2] + qv[3]*qv[3];
    float b = pv[0]*pv[0] + pv[1]*pv[1] + pv[2]*pv[2] + pv[3]*pv[3];
    float c = qv[0]*pv[0] + qv[1]*pv[1] + qv[2]*pv[2] + qv[3]*pv[3];
    #pragma unroll
    for (int off = 32; off > 0; off >>= 1) {
        a += __shfl_xor(a, off);
        b += __shfl_xor(b, off);
        c += __shfl_xor(c, off);
    }
    const float rq = 1.0f / fmaxf(sqrtf(a), 1e-12f);
    const float rp = 1.0f / fmaxf(sqrtf(b), 1e-12f);

    ushort4 zq, zp;
    zq.x = bf16_bits(qv[0] * rq); zq.y = bf16_bits(qv[1] * rq);
    zq.z = bf16_bits(qv[2] * rq); zq.w = bf16_bits(qv[3] * rq);
    zp.x = bf16_bits(pv[0] * rp); zp.y = bf16_bits(pv[1] * rp);
    zp.z = bf16_bits(pv[2] * rp); zp.w = bf16_bits(pv[3] * rp);
    *(ushort4*)(Z + (size_t)row * D_DIM + lane * 4)            = zq;
    *(ushort4*)(Z + (size_t)(B_ROWS + row) * D_DIM + lane * 4) = zp;
    if (lane == 0) pospart[row] = c * rq * rp;
}

// ---------------------------------------------------------------------------
// Kernel 2: fused S = Z*Z^T + exp-rowsum partials (collision-free stores).
// THIS ROUND: T3/T4-minimum pipeline — double-buffered LDS (2x32 KB) with
// RAW s_barrier (no vmcnt drain) + counted s_waitcnt vmcnt(8).
//   iter kt:  issue stage(kt+1) -> buf[(kt+1)&1]   (8 gload_lds/wave)
//             s_waitcnt vmcnt(8)     <- stage(kt) retired, kt+1 IN FLIGHT
//             s_barrier              <- all waves' stage(kt) committed
//             compute buf[kt&1]      (ds_read + MFMA)
//             s_barrier              <- reads done; stage(kt+2) may overwrite
// R1's dbuf failed because __syncthreads drains vmcnt(0) at every barrier
// (m97 ceiling mechanism); the counted wait keeps the prefetch in flight so
// the L2 round-trip hides under compute. Hazard ledger: stage(kt+1) vs
// compute(kt-1) on same buffer separated by iter kt-1's end barrier; per-wave
// vmcnt(8) + barrier => collective stage(kt) completion. sched_barrier(0)
// fences each sync point (rule #18: compiler hoists past asm waitcnt).
// ---------------------------------------------------------------------------
__global__ __launch_bounds__(256, 3) void simexp_gemm(
        const __hip_bfloat16* __restrict__ Z, float* __restrict__ bufP) {
    __shared__ __hip_bfloat16 As[2][128 * 64];   // 2 x 16 KB
    __shared__ __hip_bfloat16 Bs[2][128 * 64];   // 2 x 16 KB
    const int tid    = threadIdx.x;
    const int lane   = tid & 63;
    const int wv     = tid >> 6;      // wave id 0..3
    const int wave_m = wv >> 1;       // 0..1  (row half)
    const int wave_n = wv & 1;        // 0..1  (col half)
    const int m16    = lane & 15;
    const int quad   = lane >> 4;

    // --- triangular decode: bid -> (bi <= bj) ---
    const int bid = blockIdx.x;
    int bi = (int)((129.0 - sqrt(129.0 * 129.0 - 8.0 * (double)bid)) * 0.5);
    while (bi > 0 && (bi * NTILE - bi * (bi - 1) / 2) > bid) --bi;
    while (((bi + 1) * NTILE - (bi + 1) * bi / 2) <= bid) ++bi;
    const int bj = bi + (bid - (bi * NTILE - bi * (bi - 1) / 2));
    const int rowBase = bi * 128;
    const int colBase = bj * 128;

    f32x4 acc[4][4];
    #pragma unroll
    for (int i = 0; i < 4; ++i)
        #pragma unroll
        for (int j = 0; j < 4; ++j) acc[i][j] = (f32x4){0.f, 0.f, 0.f, 0.f};

    // staging geometry: one instr = 64 lanes x 16B = 8 rows of 128B.
    // lane l -> local row (l>>3), chunk slot (l&7); LDS chunk c of row r
    // holds global chunk c ^ (r&7) (xor involution). u32 byte offsets,
    // advanced +128 B per stage call (K-chunks consumed in order).
    const int lrow = lane >> 3;
    const int lchk = lane & 7;
    unsigned int aoff[4], boff[4];
    #pragma unroll
    for (int pp = 0; pp < 4; ++pp) {
        const int r = wv * 32 + pp * 8 + lrow;          // local row 0..127
        const int g = lchk ^ (r & 7);                   // swizzled global chunk
        aoff[pp] = (unsigned int)((rowBase + r) * 512 + g * 16);
        boff[pp] = (unsigned int)((colBase + r) * 512 + g * 16);
    }

    auto stage = [&](int buf) {
        #pragma unroll
        for (int pp = 0; pp < 4; ++pp) {
            async_copy16((const char*)Z + aoff[pp],
                         (char*)As[buf] + (wv * 32 + pp * 8) * 128);
            async_copy16((const char*)Z + boff[pp],
                         (char*)Bs[buf] + (wv * 32 + pp * 8) * 128);
            aoff[pp] += 128;   // next K-chunk (64 elems = 128 B)
            boff[pp] += 128;
        }
    };

    stage(0);   // prologue: K-chunk 0 -> buf 0 (8 loads in flight)

    #pragma unroll
    for (int kt = 0; kt < 4; ++kt) {
        if (kt < 3) stage((kt + 1) & 1);   // prefetch next chunk, stays in flight

        if (kt < 3) asm volatile("s_waitcnt vmcnt(8)" ::: "memory");
        else        asm volatile("s_waitcnt vmcnt(0)" ::: "memory");
        __builtin_amdgcn_s_barrier();          // all waves' stage(kt) committed
        __builtin_amdgcn_sched_barrier(0);     // no ds_read hoists above this

        const int cb = kt & 1;
        #pragma unroll
        for (int kt2 = 0; kt2 < 2; ++kt2) {
            const int sw = (kt2 * 4 + quad) ^ (m16 & 7);  // swizzled chunk
            const unsigned int abase =
                (unsigned int)((wave_m * 64 + m16) * 128 + sw * 16);
            const unsigned int bbase =
                (unsigned int)((wave_n * 64 + m16) * 128 + sw * 16);
            bf16x8 af[4], bfr[4];
            #pragma unroll
            for (int mi = 0; mi < 4; ++mi)
                af[mi] = *(const bf16x8*)((const char*)As[cb] + abase + mi * 2048);
            #pragma unroll
            for (int ni = 0; ni < 4; ++ni)
                bfr[ni] = *(const bf16x8*)((const char*)Bs[cb] + bbase + ni * 2048);
            #pragma unroll
            for (int mi = 0; mi < 4; ++mi)
                #pragma unroll
                for (int ni = 0; ni < 4; ++ni)
                    acc[mi][ni] = __builtin_amdgcn_mfma_f32_16x16x32_bf16(
                        af[mi], bfr[ni], acc[mi][ni], 0, 0, 0);
        }

        if (kt < 3) {
            __builtin_amdgcn_sched_barrier(0); // reads stay above the barrier
            __builtin_amdgcn_s_barrier();      // buf[kt&1] free for stage(kt+2)
            __builtin_amdgcn_sched_barrier(0); // next stage stays below
        }
    }

    // --- epilogue: exp(2s) once; row partials and col partials ---
    // C/D layout: col = lane&15, row = quad*4 + reg  [m89-verified].
    float cs[4] = {0.f, 0.f, 0.f, 0.f};
    float rs[4][4];
    #pragma unroll
    for (int mi = 0; mi < 4; ++mi)
        #pragma unroll
        for (int r = 0; r < 4; ++r) {
            float s = 0.f;
            #pragma unroll
            for (int ni = 0; ni < 4; ++ni) {
                const float e = __expf(2.0f * acc[mi][ni][r]);
                s += e;
                cs[ni] += e;
            }
            rs[mi][r] = s;
        }
    // row sums: reduce across the 16 columns (lanes sharing a quad)
    #pragma unroll
    for (int off = 1; off < 16; off <<= 1)
        #pragma unroll
        for (int mi = 0; mi < 4; ++mi)
            #pragma unroll
            for (int r = 0; r < 4; ++r)
                rs[mi][r] += __shfl_xor(rs[mi][r], off, 64);
    if (m16 == 0) {
        float* dst = bufP + (size_t)(2 * bj + wave_n) * N_TOT + rowBase;
        #pragma unroll
        for (int mi = 0; mi < 4; ++mi)
            #pragma unroll
            for (int r = 0; r < 4; ++r)
                dst[wave_m * 64 + mi * 16 + quad * 4 + r] = rs[mi][r];
    }
    // col sums: reduce across the 4 quads (rows) -> symmetric contribution
    if (bi != bj) {
        #pragma unroll
        for (int off = 16; off < 64; off <<= 1)
            #pragma unroll
            for (int ni = 0; ni < 4; ++ni)
                cs[ni] += __shfl_xor(cs[ni], off, 64);
        if (lane < 16) {
            float* dst = bufP + (size_t)(2 * bi + wave_m) * N_TOT + colBase;
            #pragma unroll
            for (int ni = 0; ni < 4; ++ni)
                dst[wave_n * 64 + ni * 16 + m16] = cs[ni];
        }
    }
}

// ---------------------------------------------------------------------------
// Kernel 2b (merged reduce + finalize, R11-proven, frozen): block b of 32
// owns rows r=b*256+t; 8 accumulator chains; thread 0 atomicAdds
// block_sum/8192 into out[0].
// ---------------------------------------------------------------------------
__global__ __launch_bounds__(256) void reduce_kernel(
        const float* __restrict__ bufP, const float* __restrict__ pospart,
        float* __restrict__ out) {
    const int b = blockIdx.x;                    // 0..31
    const int t = threadIdx.x;                   // 0..255
    const int r = b * 256 + t;                   // 0..8191
    float s[8] = {0.f, 0.f, 0.f, 0.f, 0.f, 0.f, 0.f, 0.f};
    #pragma unroll
    for (int k = 0; k < NSLOT; k += 8) {
        #pragma unroll
        for (int j = 0; j < 8; ++j)
            s[j] += bufP[(size_t)(k + j) * N_TOT + r];
    }
    const float denom = ((s[0] + s[1]) + (s[2] + s[3]))
                      + ((s[4] + s[5]) + (s[6] + s[7]));
    float contrib = logf(denom - E2);
    if (b < 16) contrib -= 4.0f * pospart[b * 256 + t];

    #pragma unroll
    for (int off = 32; off > 0; off >>= 1)
        contrib += __shfl_down(contrib, off);
    __shared__ float red[4];
    if ((t & 63) == 0) red[t >> 6] = contrib;
    __syncthreads();
    if (t == 0) {
        const float bs = (red[0] + red[1]) + (red[2] + red[3]);
        atomicAdd(out, bs / (float)N_TOT);
    }
}

extern "C" void kernel_launch(void* const* d_in, const int* in_sizes, int n_in,
                              void* d_out, int out_size, void* d_ws, size_t ws_size,
                              hipStream_t stream) {
    const float* q = (const float*)d_in[0];
    const float* p = (const float*)d_in[1];
    // d_in[2] (neg) is normalized in the original but never used in the loss.
    float* out = (float*)d_out;

    // Workspace layout:
    //   Z        bf16 [8192*256]  @ 0       (4 MiB)
    //   bufP     f32  [128*8192]  @ 4 MiB   (4 MiB)  exp-sum partials
    //   pospart  f32  [4096]      after bufP
    __hip_bfloat16* Z = (__hip_bfloat16*)d_ws;
    float* bufP     = (float*)((char*)d_ws + (size_t)N_TOT * D_DIM * sizeof(__hip_bfloat16));
    float* pospart  = bufP + (size_t)NSLOT * N_TOT;

    hipLaunchKernelGGL(norm_kernel, dim3(B_ROWS / 4), dim3(256), 0, stream,
                       q, p, Z, pospart, out);
    hipLaunchKernelGGL(simexp_gemm, dim3(NBLK), dim3(256), 0, stream, Z, bufP);
    hipLaunchKernelGGL(reduce_kernel, dim3(32), dim3(256), 0, stream,
                       bufP, pospart, out);
}